// Round 13
// baseline (170.817 us; speedup 1.0000x reference)
//
#include <hip/hip_runtime.h>
#include <math.h>

typedef __attribute__((ext_vector_type(8))) short bf16x8;
typedef __attribute__((ext_vector_type(16))) float f32x16;

#define Bsz 4
#define Nn 1024
#define TN 3072
#define Dd 256
#define Hh 4
#define DH 64
#define TAUc 1e-3f
#define QSCALE 0.1803368801111f   // log2(e)/8 : softmax done in exp2 domain

// workspace layout (float offsets)
#define SALP_OFF 0           // 98304 (4 b x 96 slabs x 256 d partial sums)
#define IDX_OFF  98304       // 256 ints
#define XCB_OFF  98560       // bf16 (4,3072,64) = 393216 floats
#define WCT_OFF  491776      // bf16 (4,3,256,64) = 98304 floats
#define QB_OFF   590080      // bf16 (16,3072,64) linear
#define KB_OFF   2162944     // bf16 (16 bh,24 tiles,128 row,8 chunk,8) swizzled tiles
#define VT_OFF   3735808     // bf16 (16 bh,24 tiles,64 row,16 chunk,8) swizzled tiles
#define OP0_OFF  5308672     // fp32 (4,3072,256) split-K partial 0
#define OP1_OFF  8454400     // fp32 partial 1
#define SML_OFF  11600128    // float [2][16][3072] row sums l
#define WOP_OFF  11698432    // uint [256 dout][128 hi | 128 lo] packed Wo bf16
                             // (ws_size >= 72MB proven by r10/r11 nspl=4 runs)

__device__ __forceinline__ ushort f2b(float f) {
    uint u = __float_as_uint(f);
    u += 0x7fffu + ((u >> 16) & 1u);
    return (ushort)(u >> 16);
}
__device__ __forceinline__ uint pk2(float a, float b) {   // RNE pack (software)
    return (uint)f2b(a) | ((uint)f2b(b) << 16);
}
__device__ __forceinline__ uint trunc_pk(float a, float b) {
    return (__float_as_uint(a) >> 16) | (__float_as_uint(b) & 0xFFFF0000u);
}
__device__ __forceinline__ float hi_f(float a) {
    return __uint_as_float(__float_as_uint(a) & 0xFFFF0000u);
}
__device__ __forceinline__ uint cvtpk(float a, float b) {  // HW RNE pack
    uint r;
    asm("v_cvt_pk_bf16_f32 %0, %1, %2" : "=v"(r) : "v"(a), "v"(b));
    return r;
}
// raw v_exp_f32 WITHOUT libm's denorm/range-guard expansion, via the compiler
// builtin so TRANS-op hazard NOPs are inserted (r2 lesson: inline-asm
// v_exp_f32 loses the mandatory TRANS->VALU wait state -> stale reads).
__device__ __forceinline__ float ex2(float x) {
    return __builtin_amdgcn_exp2f(x);
}
// async global->LDS DMA, 16B per lane (lane-linear LDS destination)
__device__ __forceinline__ void gld16(const ushort* g, ushort* l) {
    __builtin_amdgcn_global_load_lds(
        (const __attribute__((address_space(1))) uint*)g,
        (__attribute__((address_space(3))) uint*)l, 16, 0, 0);
}
union U4B8 { uint u[4]; bf16x8 v; };
__device__ __forceinline__ bf16x8 ld8(const ushort* p) { return *(const bf16x8*)p; }

// ---- kernel 1: per-channel saliency partial sums ----
__global__ __launch_bounds__(256) void k_sal(
        const float* __restrict__ F0, const float* __restrict__ F1,
        const float* __restrict__ F2, float* __restrict__ salp) {
    int b = blockIdx.x / 96;
    int slab = blockIdx.x - b * 96;
    int t0 = slab * 32;
    int seg = t0 >> 10, tt0 = t0 & 1023;
    const float* F = (seg == 0) ? F0 : (seg == 1 ? F1 : F2);
    const float* base = &F[(size_t)((b << 10) + tt0) * Dd + threadIdx.x];
    float acc = 0.f;
    #pragma unroll 4
    for (int r = 0; r < 32; ++r) {
        float x = base[(size_t)r * Dd];
        acc += fmaxf(fabsf(x) - TAUc, 0.f);
    }
    salp[blockIdx.x * 256 + threadIdx.x] = acc;
}

// ---- kernel 2: reduce partials + top-64 (r13: shfl-bitonic, 45 -> 7 barriers)
// Reduction loop is BYTE-IDENTICAL to r12 (FP order preserved -> same sal
// values -> same selection). Sort restructured: steps with j<=32 are
// intra-wave -> register compare-exchange via __shfl_xor (no LDS, no
// barrier); only the 3 cross-wave steps (j>=64) use LDS+barriers.
// Sorting permutes values only -> v[192] bitwise-identical to r12.
__global__ void k_topk(const float* __restrict__ salp, int* __restrict__ idx) {
    __shared__ float xw[256];
    __shared__ float thrs;
    __shared__ int cnt;
    int b = blockIdx.x, tid = threadIdx.x;
    float myval = 0.f;
    const float* p = &salp[(size_t)b * 96 * 256 + tid];
    #pragma unroll 4
    for (int s = 0; s < 96; ++s) myval += p[s * 256];
    if (tid == 0) cnt = 0;
    float v = myval;
    for (int k = 2; k <= 256; k <<= 1) {
        for (int j = k >> 1; j > 0; j >>= 1) {
            bool up = ((tid & k) == 0);
            float ov;
            if (j >= 64) {
                xw[tid] = v;
                __syncthreads();
                ov = xw[tid ^ j];
                __syncthreads();        // reads done before next xw write
            } else {
                ov = __shfl_xor(v, j);  // partner within the 64-lane wave
            }
            bool lowhalf = ((tid & j) == 0);
            // lower index keeps min iff ascending (matches r12 comparator)
            v = (lowhalf == up) ? fminf(v, ov) : fmaxf(v, ov);
        }
    }
    if (tid == 192) thrs = v;           // ascending: rank-193 = 64th largest
    __syncthreads();
    float thr = thrs;
    if (myval >= thr) {
        int p2 = atomicAdd(&cnt, 1);
        if (p2 < 64) idx[b * 64 + p2] = tid;
    }
}

// ---- kernel 3: merged gathers (0..383: X; 384..767: W columns;
// 768..831 (r13): Wo -> packed hi/lo bf16 prep, hoisted out of k_out) ----
__global__ __launch_bounds__(256) void k_gather(
        const float* __restrict__ F0, const float* __restrict__ F1,
        const float* __restrict__ F2,
        const float* __restrict__ Wq, const float* __restrict__ Wk,
        const float* __restrict__ Wv, const float* __restrict__ Wo,
        const int* __restrict__ idx,
        uint* __restrict__ Xcb, uint* __restrict__ Wct,
        uint* __restrict__ Wop) {
    __shared__ float xs[32 * 260];
    __shared__ int ids[64];
    int tid = threadIdx.x;
    if (blockIdx.x < 384) {
        int b = blockIdx.x / 96;
        int t0 = (blockIdx.x - b * 96) * 32;
        if (tid < 64) ids[tid] = idx[b * 64 + tid];
        int seg = t0 >> 10, tt0 = t0 & 1023;
        const float* F = (seg == 0) ? F0 : (seg == 1 ? F1 : F2);
        const float* base = &F[(size_t)((b << 10) + tt0) * Dd];
        #pragma unroll
        for (int i = 0; i < 8; ++i) {
            int i0 = tid + i * 256;
            int r = i0 >> 6, c4 = (i0 & 63) << 2;
            float4 x = *(const float4*)&base[(size_t)r * Dd + c4];
            x.x = copysignf(fmaxf(fabsf(x.x) - TAUc, 0.f), x.x);
            x.y = copysignf(fmaxf(fabsf(x.y) - TAUc, 0.f), x.y);
            x.z = copysignf(fmaxf(fabsf(x.z) - TAUc, 0.f), x.z);
            x.w = copysignf(fmaxf(fabsf(x.w) - TAUc, 0.f), x.w);
            *(float4*)&xs[r * 260 + c4] = x;
        }
        __syncthreads();
        #pragma unroll
        for (int i = 0; i < 4; ++i) {
            int i0 = tid + i * 256;
            int r = i0 >> 5, jp = i0 & 31;
            float x0 = xs[r * 260 + ids[2 * jp]];
            float x1 = xs[r * 260 + ids[2 * jp + 1]];
            Xcb[(size_t)(b * TN + t0 + r) * 32 + jp] = pk2(x0, x1);
        }
    } else if (blockIdx.x < 768) {
        int gid = (blockIdx.x - 384) * 256 + tid;   // 98304
        int b = gid / 24576;
        if (tid < 64) ids[tid] = idx[b * 64 + tid];
        __syncthreads();
        int rem = gid - b * 24576;
        int mat = rem / 8192;
        int rem2 = rem - mat * 8192;
        int dout = rem2 >> 5, jp = rem2 & 31;
        const float* Wm = (mat == 0) ? Wq : (mat == 1 ? Wk : Wv);
        float w0 = Wm[(size_t)dout * 256 + ids[2 * jp]];
        float w1 = Wm[(size_t)dout * 256 + ids[2 * jp + 1]];
        Wct[((size_t)(b * 3 + mat) * 256 + dout) * 32 + jp] = pk2(w0, w1);
    } else {
        // Wo prep: 64 blocks x 256 threads = 16384 = 256 dout x 64 groups.
        // Same trunc_pk values k_out used to compute per-block -> bit-identical.
        int gid2 = (blockIdx.x - 768) * 256 + tid;
        int dout = gid2 >> 6, g = gid2 & 63;
        float4 w = *(const float4*)&Wo[(size_t)dout * 256 + g * 4];
        uint* row = &Wop[(size_t)dout * 256];
        row[g * 2]       = trunc_pk(w.x, w.y);
        row[g * 2 + 1]   = trunc_pk(w.z, w.w);
        row[128 + g * 2] = trunc_pk(w.x - hi_f(w.x), w.y - hi_f(w.y));
        row[128 + g * 2 + 1] = trunc_pk(w.z - hi_f(w.z), w.w - hi_f(w.w));
    }
}

// ---- kernel 4: QKV projection, 32x32x16 MFMA, LDS-free ----
// Q: linear (b,h,t,d), pre-scaled. K/V: written directly in the SWIZZLED TILE
// layout k_attn's LDS image uses, so k_attn can DMA tiles with global_load_lds.
__global__ __launch_bounds__(256) void k_qkv(
        const ushort* __restrict__ Xcb, const ushort* __restrict__ Wct,
        const float* __restrict__ bq, const float* __restrict__ bk,
        const float* __restrict__ bv,
        ushort* __restrict__ Qh, ushort* __restrict__ Kh, ushort* __restrict__ Vt) {
    int wave = threadIdx.x >> 6, lane = threadIdx.x & 63;
    int l31 = lane & 31, h = lane >> 5;
    int W = blockIdx.x * 4 + wave;          // 2304 wave-tasks
    int b = W / 576;
    int r = W - b * 576;
    int mat = r / 192;
    int p = r - mat * 192;
    const ushort* Xb = Xcb + (size_t)b * TN * 64;
    const ushort* Wm = Wct + (size_t)(b * 3 + mat) * 256 * 64;
    f32x16 c[4];
    #pragma unroll
    for (int nt = 0; nt < 4; ++nt)
        #pragma unroll
        for (int q = 0; q < 16; ++q) c[nt][q] = 0.f;
    if (mat < 2) {
        int mtt = p % 96, ng = p / 96;      // t tile, dout half
        const ushort* arow = &Xb[(size_t)(mtt * 32 + l31) * 64];
        #pragma unroll
        for (int kc = 0; kc < 4; ++kc) {
            bf16x8 af = ld8(arow + kc * 16 + 8 * h);
            #pragma unroll
            for (int nt = 0; nt < 4; ++nt) {
                bf16x8 bf = ld8(&Wm[(size_t)(ng * 128 + nt * 32 + l31) * 64 + kc * 16 + 8 * h]);
                c[nt] = __builtin_amdgcn_mfma_f32_32x32x16_bf16(af, bf, c[nt], 0, 0, 0);
            }
        }
        if (mat == 0) {
            // Q: linear coalesced stores, pre-scaled
            #pragma unroll
            for (int nt = 0; nt < 4; ++nt) {
                int dout = ng * 128 + nt * 32 + l31;
                int head = dout >> 6, d63 = dout & 63;
                float bb = bq[dout];
                size_t obase = ((size_t)(b * 4 + head) * TN + mtt * 32) * 64 + d63;
                #pragma unroll
                for (int u = 0; u < 16; ++u) {
                    int trow = (u & 3) + 8 * (u >> 2) + 4 * h;
                    Qh[obase + (size_t)trow * 64] = f2b((c[nt][u] + bb) * QSCALE);
                }
            }
        } else {
            // K: swizzled tile layout: [bh][tile=t>>7][row=t&127][chunk=(d>>3)^fk][d&7]
            #pragma unroll
            for (int nt = 0; nt < 4; ++nt) {
                int dout = ng * 128 + nt * 32 + l31;
                int head = dout >> 6, d63 = dout & 63;
                float bb = bk[dout];
                size_t base = (size_t)(b * 4 + head) * 196608;
                #pragma unroll
                for (int u = 0; u < 16; ++u) {
                    int trow = (u & 3) + 8 * (u >> 2) + 4 * h;
                    int t = mtt * 32 + trow;
                    int row = t & 127, tile = t >> 7;
                    int fk = (row ^ (row >> 3)) & 7;
                    Kh[base + (size_t)tile * 8192 + row * 64 +
                       (((d63 >> 3) ^ fk) << 3) + (d63 & 7)] = f2b(c[nt][u] + bb);
                }
            }
        }
    } else {
        int mtv = p & 7, tg = p >> 3;       // dout tile (8), t group (24 = key tile)
        const ushort* arow = &Wm[(size_t)(mtv * 32 + l31) * 64];
        #pragma unroll
        for (int kc = 0; kc < 4; ++kc) {
            bf16x8 af = ld8(arow + kc * 16 + 8 * h);
            #pragma unroll
            for (int nt = 0; nt < 4; ++nt) {
                bf16x8 bf = ld8(&Xb[(size_t)(tg * 128 + nt * 32 + l31) * 64 + kc * 16 + 8 * h]);
                c[nt] = __builtin_amdgcn_mfma_f32_32x32x16_bf16(af, bf, c[nt], 0, 0, 0);
            }
        }
        int head = mtv >> 1;
        int sl = (l31 & 19) | ((l31 & 4) << 1) | ((l31 & 8) >> 1);  // swap bits 2<->3
        size_t vbase = (size_t)(b * 4 + head) * 196608 + (size_t)tg * 8192;
        // V: swizzled tile: [bh][tile=tg][row=d&63][chunk'=(c&8)|((c&7)^fv)][key&7]
        #pragma unroll
        for (int nt = 0; nt < 4; ++nt) {
            int cc = (nt * 32 + sl) >> 3;   // key chunk within tile (0..15)
            int elem = sl & 7;
            #pragma unroll
            for (int u = 0; u < 16; ++u) {
                int dout = mtv * 32 + (u & 3) + 8 * (u >> 2) + 4 * h;
                int row = dout & 63;
                int fv = (row ^ (row >> 3)) & 7;
                int ch = (cc & 8) | ((cc & 7) ^ fv);
                Vt[vbase + row * 128 + ch * 8 + elem] = f2b(c[nt][u] + bv[dout]);
            }
        }
    }
}

// ---- kernel 5: flash attention — r7 verbatim (twice-verified, 48.3-49.6us,
// absmax 4.88e-4). 64-key tiles, 2-buffer LDS, XCD-locality remap, slim
// softmax, intra-tile QK/exp/PV interleave. Measured plateau: latency-bound
// at 3 blocks/CU (natural 144-reg footprint); register-cap occupancy refuted
// (r10/r11 spills); cross-tile pipelines race (r5/r6).
__global__ __launch_bounds__(256, 3) void k_attn(
        const ushort* __restrict__ Qg, const ushort* __restrict__ Kg,
        const ushort* __restrict__ Vtg,
        float* __restrict__ OP0, float* __restrict__ OP1,
        float* __restrict__ Sml) {
    __shared__ __align__(16) ushort Ks[2][64 * 64];    // [buf][key row][d] swizzled
    __shared__ __align__(16) ushort Vts[2][64 * 64];   // [buf][d row][key] swizzled
    // XCD-aware remap: each XCD serves exactly 2 bh (K/V/Q L2-resident).
    int bid = blockIdx.x;
    int xcd = bid & 7, j0 = bid >> 3;           // j0 in 0..95
    int bh = xcd * 2 + (j0 / 48);
    int rem = j0 % 48;
    int qt = rem >> 1, ksplit = rem & 1;
    int b = bh >> 2, hh = bh & 3;
    int tid = threadIdx.x, wave = tid >> 6, lane = tid & 63;
    int l31 = lane & 31, h = lane >> 5;
    int q0 = qt * 128 + wave * 32;
    const ushort* Qb = Qg + ((size_t)bh * TN + q0 + l31) * DH;
    bf16x8 qf[4];
    #pragma unroll
    for (int kc = 0; kc < 4; ++kc) qf[kc] = ld8(&Qb[kc * 16 + 8 * h]);

    const ushort* Ktb = Kg + (size_t)bh * 196608 + (size_t)ksplit * 98304;
    const ushort* Vtb = Vtg + (size_t)bh * 196608 + (size_t)ksplit * 98304;

    // per-thread DMA offsets (ushort units). K half-tile: 4096 contiguous.
    // V half-tile: 64 rows x 64 (rows strided 128 in the 128-key source tile).
    int koff0 = tid * 8, koff1 = tid * 8 + 2048;
    int voff0 = (tid >> 3) * 128 + (tid & 7) * 8;
    int voff1 = voff0 + 4096;                       // rows 32..63

    f32x16 o0, o1;
    #pragma unroll
    for (int q = 0; q < 16; ++q) { o0[q] = 0.f; o1[q] = 0.f; }
    f32x16 zf;                 // loop-invariant zero C-operand for QK MFMAs
    #pragma unroll
    for (int q = 0; q < 16; ++q) zf[q] = 0.f;
    float lrun = 0.f;

    int fq0 = (l31 ^ (l31 >> 3)) & 7;
    int fq1 = ((32 + l31) ^ ((32 + l31) >> 3)) & 7;
    int r0c = l31 * 64, r1c = (32 + l31) * 64;

    auto stage = [&](int ht, ushort* KsD, ushort* VtsD) {
        const ushort* ksrc = Ktb + (size_t)ht * 4096;
        const ushort* vsrc = Vtb + (size_t)((ht >> 1) * 8192 + (ht & 1) * 64);
        gld16(ksrc + koff0, KsD + koff0);
        gld16(ksrc + koff1, KsD + koff1);
        gld16(vsrc + voff0, VtsD + koff0);
        gld16(vsrc + voff1, VtsD + koff1);
    };

    auto compute = [&](const ushort* KsB, const ushort* VtsB) {
        f32x16 s0, s1;
        __builtin_amdgcn_s_setprio(1);
        // QK for keys 0-31 (s0) first...
        {
            bf16x8 k0 = ld8(&KsB[r0c + ((h ^ fq0) << 3)]);
            s0 = __builtin_amdgcn_mfma_f32_32x32x16_bf16(k0, qf[0], zf, 0, 0, 0);
        }
        #pragma unroll
        for (int kc = 1; kc < 4; ++kc) {
            bf16x8 k0 = ld8(&KsB[r0c + (((2 * kc + h) ^ fq0) << 3)]);
            s0 = __builtin_amdgcn_mfma_f32_32x32x16_bf16(k0, qf[kc], s0, 0, 0, 0);
        }
        // ...then keys 32-63 (s1): s0's last MFMA drains under these issues.
        {
            bf16x8 k1 = ld8(&KsB[r1c + ((h ^ fq1) << 3)]);
            s1 = __builtin_amdgcn_mfma_f32_32x32x16_bf16(k1, qf[0], zf, 0, 0, 0);
        }
        #pragma unroll
        for (int kc = 1; kc < 4; ++kc) {
            bf16x8 k1 = ld8(&KsB[r1c + (((2 * kc + h) ^ fq1) << 3)]);
            s1 = __builtin_amdgcn_mfma_f32_32x32x16_bf16(k1, qf[kc], s1, 0, 0, 0);
        }
        __builtin_amdgcn_s_setprio(0);
        U4B8 pk4[4];
        float ps0 = 0.f, ps1 = 0.f, ps2 = 0.f, ps3 = 0.f;
        // exp(s0): overlaps s1's MFMA drain
        #pragma unroll
        for (int u = 0; u < 8; ++u) {
            float pa = ex2(s0[2 * u]), pb = ex2(s0[2 * u + 1]);
            ps0 += pa; ps1 += pb;
            pk4[u >> 2].u[u & 3] = cvtpk(pa, pb);
        }
        // PV chunks 0-1 need only pk4[0..1] (s0-derived): issue them now so
        // the matrix pipe works while exp(s1) runs on the TRANS pipe.
        __builtin_amdgcn_s_setprio(1);
        #pragma unroll
        for (int kc2 = 0; kc2 < 2; ++kc2) {
            int ch = 2 * kc2 + h;
            bf16x8 v0f = ld8(&VtsB[r0c + ((ch ^ fq0) << 3)]);
            bf16x8 v1f = ld8(&VtsB[r1c + ((ch ^ fq1) << 3)]);
            o0 = __builtin_amdgcn_mfma_f32_32x32x16_bf16(pk4[kc2].v, v0f, o0, 0, 0, 0);
            o1 = __builtin_amdgcn_mfma_f32_32x32x16_bf16(pk4[kc2].v, v1f, o1, 0, 0, 0);
        }
        __builtin_amdgcn_s_setprio(0);
        // exp(s1): overlaps PV(0-1) MFMAs
        #pragma unroll
        for (int u = 0; u < 8; ++u) {
            float pa = ex2(s1[2 * u]), pb = ex2(s1[2 * u + 1]);
            ps2 += pa; ps3 += pb;
            pk4[2 + (u >> 2)].u[u & 3] = cvtpk(pa, pb);
        }
        lrun += (ps0 + ps1) + (ps2 + ps3);
        __builtin_amdgcn_s_setprio(1);
        #pragma unroll
        for (int kc2 = 2; kc2 < 4; ++kc2) {
            int ch = 2 * kc2 + h;
            bf16x8 v0f = ld8(&VtsB[r0c + ((ch ^ fq0) << 3)]);
            bf16x8 v1f = ld8(&VtsB[r1c + ((ch ^ fq1) << 3)]);
            o0 = __builtin_amdgcn_mfma_f32_32x32x16_bf16(pk4[kc2].v, v0f, o0, 0, 0, 0);
            o1 = __builtin_amdgcn_mfma_f32_32x32x16_bf16(pk4[kc2].v, v1f, o1, 0, 0, 0);
        }
        __builtin_amdgcn_s_setprio(0);
    };

    // prologue: fill buffer 0; __syncthreads drains vmcnt(0) + makes it visible
    stage(0, Ks[0], Vts[0]);
    __syncthreads();
    #pragma unroll 1
    for (int t = 0; t < 24; t += 2) {
        stage(t + 1, Ks[1], Vts[1]);        // async: flies under compute(buf0)
        compute(Ks[0], Vts[0]);
        __syncthreads();                    // vmcnt(0): buf1 ready; buf0 free
        if (t + 2 < 24) stage(t + 2, Ks[0], Vts[0]);
        compute(Ks[1], Vts[1]);
        __syncthreads();                    // vmcnt(0): buf0 ready; buf1 free
    }

    // one cross-half combine instead of per-tile (sum over tiles commutes)
    lrun += __shfl_xor(lrun, 32);

    float* OP = ksplit ? OP1 : OP0;
    #pragma unroll
    for (int q = 0; q < 16; ++q) {
        int qrow = (q & 3) + 8 * (q >> 2) + 4 * h;
        int t = q0 + qrow;
        size_t base = ((size_t)b * TN + t) * Dd + hh * 64;
        OP[base + l31] = o0[q];
        OP[base + 32 + l31] = o1[q];
    }
    if (h == 0)
        Sml[(size_t)ksplit * 49152 + (size_t)bh * TN + q0 + l31] = lrun;
}

// ---- kernel 6: output projection — r13: W hi/lo fragments PRELOADED from
// Wop (prepared once in k_gather; bit-identical trunc_pk values) instead of
// per-block fp32 load + ~400 VALU conversion instrs/thread. Rest unchanged:
// double-buffered LDS, XOR-swizzled M tile, split-bf16 MFMA, fused combine.
// Grid (192,4): 4 dout-blocks sharing OP token rows are 192 apart
// (192 % 8 == 0) -> same XCD -> OP re-reads are L2 hits.
__global__ __launch_bounds__(256) void k_out(
        const float* __restrict__ OP0, const float* __restrict__ OP1,
        const float* __restrict__ Sml, const uint* __restrict__ Wop,
        const float* __restrict__ bo, float* __restrict__ out) {
    __shared__ __align__(16) ushort Ms[2][64][64];   // [buf][t][8 chunks: hi 0-3, lo 4-7]
    __shared__ float invsh[64 * 4];
    int nd4 = blockIdx.y;              // 64-dout group (4)
    int R0 = blockIdx.x * 64;          // 64-token group (192)
    int b = R0 / TN;
    int tloc0 = R0 - b * TN;
    int tid = threadIdx.x, wave = tid >> 6, lane = tid & 63;
    int l31 = lane & 31, h = lane >> 5;
    int wt = wave & 1, wd = wave >> 1;
    {
        int hd = tid >> 6, t = tid & 63;
        size_t o = (size_t)(b * 4 + hd) * TN + tloc0 + t;
        invsh[t * 4 + hd] = 1.f / (Sml[o] + Sml[49152 + o]);
    }
    int dout = nd4 * 64 + wd * 32 + l31;
    float bb = bo[dout];
    const uint* wrow = &Wop[(size_t)dout * 256];   // [128 hi | 128 lo] uints
    int st_t = tid >> 2, st_c = tid & 3;
    int fst = (st_t ^ (st_t >> 3)) & 7;
    size_t gbase = ((size_t)(b * TN + tloc0 + st_t)) * 256 + st_c * 8;
    int trow = wt * 32 + l31;
    int ftr = (trow ^ (trow >> 3)) & 7;
    f32x16 acc;
    #pragma unroll
    for (int q = 0; q < 16; ++q) acc[q] = 0.f;

    auto stage_load = [&](int st, int buf) {
        size_t ob = gbase + (size_t)st * 32;
        float4 x0 = *(const float4*)&OP0[ob];
        float4 x1 = *(const float4*)&OP0[ob + 4];
        float4 y0 = *(const float4*)&OP1[ob];
        float4 y1 = *(const float4*)&OP1[ob + 4];
        float s = invsh[st_t * 4 + (st >> 1)];
        float m0 = (x0.x + y0.x) * s, m1 = (x0.y + y0.y) * s;
        float m2 = (x0.z + y0.z) * s, m3 = (x0.w + y0.w) * s;
        float m4 = (x1.x + y1.x) * s, m5 = (x1.y + y1.y) * s;
        float m6 = (x1.z + y1.z) * s, m7 = (x1.w + y1.w) * s;
        uint4 hi = { trunc_pk(m0, m1), trunc_pk(m2, m3),
                     trunc_pk(m4, m5), trunc_pk(m6, m7) };
        uint4 lo = { trunc_pk(m0 - hi_f(m0), m1 - hi_f(m1)),
                     trunc_pk(m2 - hi_f(m2), m3 - hi_f(m3)),
                     trunc_pk(m4 - hi_f(m4), m5 - hi_f(m5)),
                     trunc_pk(m6 - hi_f(m6), m7 - hi_f(m7)) };
        *(uint4*)&Ms[buf][st_t][(st_c ^ fst) * 8] = hi;
        *(uint4*)&Ms[buf][st_t][((4 + st_c) ^ fst) * 8] = lo;
    };

    __syncthreads();            // invsh visible
    stage_load(0, 0);
    #pragma unroll 1
    for (int st = 0; st < 8; ++st) {
        __syncthreads();        // buf[st&1] visible; previous reads complete
        if (st < 7) stage_load(st + 1, (st + 1) & 1);
        int buf = st & 1;
        #pragma unroll
        for (int kc = 0; kc < 2; ++kc) {
            bf16x8 ah = *(const bf16x8*)&Ms[buf][trow][((2 * kc + h) ^ ftr) * 8];
            bf16x8 al = *(const bf16x8*)&Ms[buf][trow][((4 + 2 * kc + h) ^ ftr) * 8];
            int din0 = st * 32 + kc * 16 + 8 * h;
            bf16x8 whv = *(const bf16x8*)&wrow[din0 >> 1];         // hi frag
            bf16x8 wlv = *(const bf16x8*)&wrow[128 + (din0 >> 1)]; // lo frag
            acc = __builtin_amdgcn_mfma_f32_32x32x16_bf16(ah, whv, acc, 0, 0, 0);
            acc = __builtin_amdgcn_mfma_f32_32x32x16_bf16(al, whv, acc, 0, 0, 0);
            acc = __builtin_amdgcn_mfma_f32_32x32x16_bf16(ah, wlv, acc, 0, 0, 0);
        }
    }
    #pragma unroll
    for (int u = 0; u < 16; ++u) {
        int tloc = tloc0 + wt * 32 + (u & 3) + 8 * (u >> 2) + 4 * h;
        int chunk = tloc >> 10, tt = tloc & 1023;
        out[(size_t)chunk * (Bsz * Nn * Dd) + ((size_t)(b * Nn + tt)) * Dd + dout] =
            acc[u] + bb;
    }
}

extern "C" void kernel_launch(void* const* d_in, const int* in_sizes, int n_in,
                              void* d_out, int out_size, void* d_ws, size_t ws_size,
                              hipStream_t stream) {
    const float* F0 = (const float*)d_in[0];
    const float* F1 = (const float*)d_in[1];
    const float* F2 = (const float*)d_in[2];
    const float* Wq = (const float*)d_in[3];
    const float* bq = (const float*)d_in[4];
    const float* Wk = (const float*)d_in[5];
    const float* bk = (const float*)d_in[6];
    const float* Wv = (const float*)d_in[7];
    const float* bv = (const float*)d_in[8];
    const float* Wo = (const float*)d_in[9];
    const float* bo = (const float*)d_in[10];
    float* ws = (float*)d_ws;
    float* out = (float*)d_out;

    int* idxp = (int*)(ws + IDX_OFF);
    uint* Xcb = (uint*)(ws + XCB_OFF);
    uint* Wct = (uint*)(ws + WCT_OFF);
    ushort* Qb16 = (ushort*)(ws + QB_OFF);
    ushort* Kb16 = (ushort*)(ws + KB_OFF);
    ushort* Vt16 = (ushort*)(ws + VT_OFF);
    float* OP0 = ws + OP0_OFF;
    float* OP1 = ws + OP1_OFF;
    float* Sml = ws + SML_OFF;
    uint* Wop = (uint*)(ws + WOP_OFF);

    k_sal<<<384, 256, 0, stream>>>(F0, F1, F2, ws + SALP_OFF);
    k_topk<<<Bsz, 256, 0, stream>>>(ws + SALP_OFF, idxp);
    k_gather<<<832, 256, 0, stream>>>(F0, F1, F2, Wq, Wk, Wv, Wo, idxp,
                                      Xcb, Wct, Wop);
    k_qkv<<<576, 256, 0, stream>>>((const ushort*)Xcb, (const ushort*)Wct,
                                   bq, bk, bv, Qb16, Kb16, Vt16);
    k_attn<<<768, 256, 0, stream>>>(Qb16, Kb16, Vt16, OP0, OP1, Sml);
    k_out<<<dim3(192, 4), 256, 0, stream>>>(OP0, OP1, Sml, Wop, bo, out);
}